// Round 1
// 217.147 us; speedup vs baseline: 1.0728x; 1.0728x over previous
//
#include <hip/hip_runtime.h>

constexpr int kRows  = 4096;
constexpr int kCols  = 11008;
constexpr int kRank  = 32;
constexpr int kHalfF = 22544384;   // kRows*kCols/2 : flat index where codebook 1 starts

constexpr int RT    = 32;    // rows per block tile
constexpr int CT    = 256;   // cols per block tile (11008 = 43 * 256, exact)
constexpr int PITCH = 260;   // corr LDS pitch: breaks bank-stride, 260*4B = 65*16B keeps b128 alignment

typedef __attribute__((ext_vector_type(8))) short short8;   // 8 x bf16 MFMA frag
typedef __attribute__((ext_vector_type(4))) float f32x4;    // MFMA accumulator

__device__ __forceinline__ unsigned short bf16_rne(float x) {
    union { float f; unsigned u; } v; v.f = x;
    return (unsigned short)((v.u + 0x7FFFu + ((v.u >> 16) & 1u)) >> 16);
}

// ---- prep: one-shot bf16 conversion of L and R (R transposed) into workspace ----
// Rbt[j][k] = bf16(R[k][j])  (11008 x 32)  -> B-frag loads become contiguous 16B
// Lb [i][k] = bf16(L[i][k])  (4096  x 32)  -> A-frag loads become contiguous 16B
__global__ __launch_bounds__(256) void prep(
    const float* __restrict__ Lm,
    const float* __restrict__ Rm,
    unsigned short* __restrict__ Lb,
    unsigned short* __restrict__ Rbt)
{
    const int tid = threadIdx.x;
    const int b   = blockIdx.x;
    if (b < 43) {                       // R transpose: 43*256 = 11008 threads, one col each
        const int j = b * 256 + tid;
        #pragma unroll
        for (int t = 0; t < 4; ++t) {
            short8 o;
            #pragma unroll
            for (int k = 0; k < 8; ++k)                       // coalesced across lanes per k
                o[k] = (short)bf16_rne(Rm[(t * 8 + k) * kCols + j]);
            *(short8*)(Rbt + j * kRank + t * 8) = o;          // 16B aligned
        }
    } else {                            // L convert: 64 blocks * 256 threads * 8 elems = 131072
        const int t0 = ((b - 43) * 256 + tid) * 8;
        const float4 a0 = *(const float4*)(Lm + t0);
        const float4 a1 = *(const float4*)(Lm + t0 + 4);
        short8 o;
        o[0] = (short)bf16_rne(a0.x); o[1] = (short)bf16_rne(a0.y);
        o[2] = (short)bf16_rne(a0.z); o[3] = (short)bf16_rne(a0.w);
        o[4] = (short)bf16_rne(a1.x); o[5] = (short)bf16_rne(a1.y);
        o[6] = (short)bf16_rne(a1.z); o[7] = (short)bf16_rne(a1.w);
        *(short8*)(Lb + t0) = o;
    }
}

__global__ __launch_bounds__(256) void qw_fused(
    const float* __restrict__ codebooks,         // (2,256,8) fp32
    const int*   __restrict__ codes,             // flat 5,636,096 int32
    const float* __restrict__ scales,            // (11008,)
    const unsigned short* __restrict__ Lb,       // (4096,32) bf16
    const unsigned short* __restrict__ Rbt,      // (11008,32) bf16 (R transposed)
    float* __restrict__ outp)                    // (4096,11008) fp32
{
    __shared__ __attribute__((aligned(16))) float cb_lds[2 * 256 * 8];  // 16 KB codebooks
    __shared__ __attribute__((aligned(16))) float corr[RT * PITCH];     // 33 KB fp32 low-rank corr tile

    const int tid = threadIdx.x;
    const int i0 = blockIdx.y * RT;
    const int j0 = blockIdx.x * CT;

    // ---- stage codebooks to LDS (4096 floats = 1024 float4) ----
    {
        const float4* src = (const float4*)codebooks;
        float4* dst = (float4*)cb_lds;
        #pragma unroll
        for (int t = 0; t < 4; ++t) dst[tid + t * 256] = src[tid + t * 256];
    }

    // ---- phase 1: corr = L[i0:i0+32,:] @ R[:, j0:j0+256] via pre-converted bf16 frags ----
    {
        const int wave = tid >> 6;
        const int lane = tid & 63;
        const int n16  = lane & 15;       // m (A) / n (B) / col (C)
        const int q    = lane >> 4;       // quad -> k-base q*8

        // A frag: Lb[(i0 + (wave&1)*16 + n16)][q*8 .. q*8+7] -- one 16B load
        const short8 af = *(const short8*)(Lb + (i0 + ((wave & 1) << 4) + n16) * kRank + (q << 3));

        // B frags: Rbt[(j0 + NT*16 + n16)][q*8 .. q*8+7] -- eight 16B loads, issued up front
        const unsigned short* bbase =
            Rbt + (size_t)(j0 + ((wave >> 1) << 7) + n16) * kRank + (q << 3);
        short8 bf[8];
        #pragma unroll
        for (int nt = 0; nt < 8; ++nt)
            bf[nt] = *(const short8*)(bbase + nt * 16 * kRank);

        const int row_base = ((wave & 1) << 4) + (q << 2);   // C row = quad*4 + reg
        const int cbase    = ((wave >> 1) << 7) + n16;

        #pragma unroll
        for (int nt = 0; nt < 8; ++nt) {
            f32x4 acc = {0.f, 0.f, 0.f, 0.f};
            acc = __builtin_amdgcn_mfma_f32_16x16x32_bf16(af, bf[nt], acc, 0, 0, 0);
            const int ccol = cbase + nt * 16;
            #pragma unroll
            for (int r = 0; r < 4; ++r)
                corr[(row_base + r) * PITCH + ccol] = acc[r];
        }
    }

    __syncthreads();

    // ---- phase 2: dequant gather + scale + corr add + fp32 store ----
    // thread -> 4 contiguous cols; 64-lane wave stores 1 KB contiguous (perfect coalescing)
    {
        const int lane4 = (tid & 63) << 2;    // col offset in tile: 0..252 step 4
        const int rbase = tid >> 6;           // 0..3
        #pragma unroll
        for (int p = 0; p < 8; ++p) {
            const int row = rbase + (p << 2);               // covers 0..31
            const int f = (i0 + row) * kCols + j0 + lane4;  // flat output index
            const int code = codes[f >> 3];                 // flat codes index == f/8
            const int cb   = (f >= kHalfF) ? 1 : 0;
            const float scale = scales[f >> 12];
            const float4 w = *(const float4*)(cb_lds + (cb << 11) + (code << 3) + (lane4 & 4));
            const float4 c = *(const float4*)(corr + row * PITCH + lane4);
            float4 o;
            o.x = w.x * scale + c.x;
            o.y = w.y * scale + c.y;
            o.z = w.z * scale + c.z;
            o.w = w.w * scale + c.w;
            *(float4*)(outp + f) = o;   // f % 4 == 0 -> 16B aligned
        }
    }
}

extern "C" void kernel_launch(void* const* d_in, const int* in_sizes, int n_in,
                              void* d_out, int out_size, void* d_ws, size_t ws_size,
                              hipStream_t stream) {
    const float* codebooks = (const float*)d_in[0];
    const int*   codes     = (const int*)d_in[1];
    const float* scales    = (const float*)d_in[2];
    const float* Lm        = (const float*)d_in[3];
    const float* Rm        = (const float*)d_in[4];
    float* outp            = (float*)d_out;

    unsigned short* Lb  = (unsigned short*)d_ws;            // 4096*32*2   = 256 KB
    unsigned short* Rbt = Lb + kRows * kRank;               // 11008*32*2  = 688 KB

    prep<<<dim3(43 + 64), dim3(256), 0, stream>>>(Lm, Rm, Lb, Rbt);

    dim3 grid(kCols / CT, kRows / RT);   // (43, 128), exact cover
    qw_fused<<<grid, dim3(256), 0, stream>>>(codebooks, codes, scales, Lb, Rbt, outp);
}